// Round 1
// baseline (503.427 us; speedup 1.0000x reference)
//
#include <hip/hip_runtime.h>
#include <math.h>

#define B_ 8
#define N_ 2048
#define D_ 3
#define H_ 256
#define ND_ (N_*D_)     // 6144
#define BN_ (B_*N_)     // 16384

// ---------------- per-batch std (ddof=1) ----------------
__global__ __launch_bounds__(256) void std_kernel(const float* __restrict__ cloud,
                                                  float* __restrict__ stdv) {
  __shared__ float red[256];
  int b = blockIdx.x, tid = threadIdx.x;
  const float* p = cloud + (size_t)b * ND_;
  float s = 0.f;
  for (int i = tid; i < ND_; i += 256) s += p[i];
  red[tid] = s; __syncthreads();
  for (int off = 128; off > 0; off >>= 1) {
    if (tid < off) red[tid] += red[tid + off];
    __syncthreads();
  }
  float mean = red[0] / (float)ND_;
  __syncthreads();
  float ss = 0.f;
  for (int i = tid; i < ND_; i += 256) { float d = p[i] - mean; ss += d * d; }
  red[tid] = ss; __syncthreads();
  for (int off = 128; off > 0; off >>= 1) {
    if (tid < off) red[tid] += red[tid + off];
    __syncthreads();
  }
  if (tid == 0) stdv[b] = sqrtf(red[0] / (float)(ND_ - 1));
}

// ---------------- pack points as (x,y,z,|p|^2), zero potentials ----------------
__global__ __launch_bounds__(256) void prep_kernel(const float* __restrict__ cloud,
    const float* __restrict__ noise, const float* __restrict__ stdv,
    float4* __restrict__ x0p, float4* __restrict__ np4,
    float* __restrict__ f, float* __restrict__ g) {
  int i = blockIdx.x * 256 + threadIdx.x;
  if (i >= BN_) return;
  int b = i >> 11;
  float sd = stdv[b];
  float cx = cloud[3*i] / sd, cy = cloud[3*i+1] / sd, cz = cloud[3*i+2] / sd;
  x0p[i] = make_float4(cx, cy, cz, cx*cx + cy*cy + cz*cz);
  float ax = noise[3*i], ay = noise[3*i+1], az = noise[3*i+2];
  np4[i] = make_float4(ax, ay, az, ax*ax + ay*ay + az*az);
  f[i] = 0.f; g[i] = 0.f;
}

// ---------------- one Sinkhorn half-iteration ----------------
// pout[i] = -eps * logsumexp_j( logw + (pin[j] - 0.5*max(|o_i|^2+|in_j|^2-2 o_i.in_j,0))/eps )
// block = 256 threads (4 waves); block handles 8 rows of one batch; wave -> 2 rows.
__global__ __launch_bounds__(256) void lse_kernel(
    const float4* __restrict__ outer, const float4* __restrict__ inner,
    const float* __restrict__ pin, float* __restrict__ pout,
    float eps, float inv_eps, float logw) {
  __shared__ float4 sPts[N_];   // 32 KB
  __shared__ float  sPot[N_];   // 8 KB
  int tid = threadIdx.x;
  int b = blockIdx.x >> 8;                 // 256 blocks per batch
  int rowBase = (blockIdx.x & 255) << 3;   // 8 rows per block
  int base = b * N_;
  for (int j = tid; j < N_; j += 256) {
    sPts[j] = inner[base + j];
    sPot[j] = pin[base + j];
  }
  __syncthreads();
  int wave = tid >> 6, lane = tid & 63;
  int r0 = rowBase + (wave << 1);
  float4 A  = outer[base + r0];
  float4 Bq = outer[base + r0 + 1];
  float v0[32], v1[32];
  float m0 = -INFINITY, m1 = -INFINITY;
#pragma unroll
  for (int jj = 0; jj < 32; ++jj) {
    int j = (jj << 6) + lane;
    float4 p = sPts[j];
    float pot = sPot[j];
    float d0 = A.x*p.x + A.y*p.y + A.z*p.z;
    float sq0 = fmaxf(A.w + p.w - 2.0f*d0, 0.0f);
    float a0 = (pot - 0.5f*sq0) * inv_eps;
    v0[jj] = a0; m0 = fmaxf(m0, a0);
    float d1 = Bq.x*p.x + Bq.y*p.y + Bq.z*p.z;
    float sq1 = fmaxf(Bq.w + p.w - 2.0f*d1, 0.0f);
    float a1 = (pot - 0.5f*sq1) * inv_eps;
    v1[jj] = a1; m1 = fmaxf(m1, a1);
  }
#pragma unroll
  for (int off = 32; off >= 1; off >>= 1) {
    m0 = fmaxf(m0, __shfl_xor(m0, off, 64));
    m1 = fmaxf(m1, __shfl_xor(m1, off, 64));
  }
  float s0 = 0.f, s1 = 0.f;
#pragma unroll
  for (int jj = 0; jj < 32; ++jj) {
    s0 += __expf(v0[jj] - m0);
    s1 += __expf(v1[jj] - m1);
  }
#pragma unroll
  for (int off = 32; off >= 1; off >>= 1) {
    s0 += __shfl_xor(s0, off, 64);
    s1 += __shfl_xor(s1, off, 64);
  }
  if (lane == 0) {
    pout[base + r0]     = -eps * (m0 + __logf(s0) + logw);
    pout[base + r0 + 1] = -eps * (m1 + __logf(s1) + logw);
  }
}

// ---------------- fused argmin(sqdist - g) + gather + interp + MLP ----------------
__global__ __launch_bounds__(256) void assign_mlp_kernel(
    const float4* __restrict__ np4, const float4* __restrict__ x0p,
    const float* __restrict__ g, const float* __restrict__ t,
    const float* __restrict__ W1, const float* __restrict__ Wt,
    const float* __restrict__ b1, const float* __restrict__ W2,
    const float* __restrict__ b2, float* __restrict__ out) {
  __shared__ float4 sPts[N_];                 // x0 points
  __shared__ float  sg[N_];
  __shared__ float  sW1[3*H_], sWt[H_], sb1[H_], sW2[H_*3], sb2[3];
  int tid = threadIdx.x;
  int b = blockIdx.x >> 8;
  int rowBase = (blockIdx.x & 255) << 3;
  int base = b * N_;
  for (int j = tid; j < N_; j += 256) { sPts[j] = x0p[base+j]; sg[j] = g[base+j]; }
  for (int i = tid; i < 3*H_; i += 256) { sW1[i] = W1[i]; sW2[i] = W2[i]; }
  if (tid < H_) { sWt[tid] = Wt[tid]; sb1[tid] = b1[tid]; }
  if (tid < 3) sb2[tid] = b2[tid];
  __syncthreads();
  int wave = tid >> 6, lane = tid & 63;
  float tb = t[b];
  for (int rr = 0; rr < 2; ++rr) {
    int r = rowBase + (wave << 1) + rr;
    float4 A = np4[base + r];
    float best = INFINITY; int bidx = 0;
#pragma unroll
    for (int jj = 0; jj < 32; ++jj) {
      int j = (jj << 6) + lane;
      float4 p = sPts[j];
      float d = A.x*p.x + A.y*p.y + A.z*p.z;
      float val = fmaxf(A.w + p.w - 2.0f*d, 0.0f) - sg[j];
      if (val < best) { best = val; bidx = j; }   // strict < keeps lowest j per lane
    }
#pragma unroll
    for (int off = 32; off >= 1; off >>= 1) {
      float ov = __shfl_xor(best, off, 64);
      int   oi = __shfl_xor(bidx, off, 64);
      if (ov < best || (ov == best && oi < bidx)) { best = ov; bidx = oi; }
    }
    float4 xa = sPts[bidx];
    float xtx = (1.0f - tb)*xa.x + tb*A.x;
    float xty = (1.0f - tb)*xa.y + tb*A.y;
    float xtz = (1.0f - tb)*xa.z + tb*A.z;
    float acc0 = 0.f, acc1 = 0.f, acc2 = 0.f;
#pragma unroll
    for (int hh = 0; hh < 4; ++hh) {
      int h = (hh << 6) + lane;
      float hv = xtx*sW1[h] + xty*sW1[H_+h] + xtz*sW1[2*H_+h] + tb*sWt[h] + sb1[h];
      hv = fmaxf(hv, 0.0f);
      acc0 += hv * sW2[3*h];
      acc1 += hv * sW2[3*h+1];
      acc2 += hv * sW2[3*h+2];
    }
#pragma unroll
    for (int off = 32; off >= 1; off >>= 1) {
      acc0 += __shfl_xor(acc0, off, 64);
      acc1 += __shfl_xor(acc1, off, 64);
      acc2 += __shfl_xor(acc2, off, 64);
    }
    if (lane == 0) {
      int gi = base + r;
      out[3*gi]   = acc0 + sb2[0];
      out[3*gi+1] = acc1 + sb2[1];
      out[3*gi+2] = acc2 + sb2[2];
      out[3*BN_ + 3*gi]   = A.x - xa.x;
      out[3*BN_ + 3*gi+1] = A.y - xa.y;
      out[3*BN_ + 3*gi+2] = A.z - xa.z;
    }
  }
}

extern "C" void kernel_launch(void* const* d_in, const int* in_sizes, int n_in,
                              void* d_out, int out_size, void* d_ws, size_t ws_size,
                              hipStream_t stream) {
  (void)in_sizes; (void)n_in; (void)out_size; (void)ws_size;
  const float* cloud = (const float*)d_in[0];
  const float* noise = (const float*)d_in[1];
  const float* t     = (const float*)d_in[2];
  const float* W1    = (const float*)d_in[3];
  const float* Wt    = (const float*)d_in[4];
  const float* b1    = (const float*)d_in[5];
  const float* b2w   = (const float*)d_in[7];
  const float* W2    = (const float*)d_in[6];
  float* out = (float*)d_out;

  float* ws   = (float*)d_ws;
  float* stdv = ws;                         // 8 floats (pad to 16)
  float4* x0p = (float4*)(ws + 16);         // BN_ float4
  float4* np4 = (float4*)(ws + 16 + 4*BN_); // BN_ float4
  float* f    = ws + 16 + 8*BN_;            // BN_
  float* g    = f + BN_;                    // BN_

  std_kernel<<<B_, 256, 0, stream>>>(cloud, stdv);
  prep_kernel<<<BN_/256, 256, 0, stream>>>(cloud, noise, stdv, x0p, np4, f, g);

  const float logw = (float)(-log(2048.0));  // loga == logb == -log(N)
  const double l0 = log10(32.0), l1 = log10(1e-6);
  for (int k = 0; k < 14; ++k) {
    // np.geomspace(32, 1e-6, 14) == 10**linspace(log10(32), -6, 14), cast fp32
    float eps = (float)pow(10.0, l0 + (l1 - l0) * ((double)k / 13.0));
    float inv_eps = 1.0f / eps;
    // f = -eps*lse_j(logb + (g - C)/eps): rows = noise, inner = x0/g
    lse_kernel<<<B_*(N_/8), 256, 0, stream>>>(np4, x0p, g, f, eps, inv_eps, logw);
    // g = -eps*lse_i(loga + (f - C)/eps): rows = x0, inner = noise/f
    lse_kernel<<<B_*(N_/8), 256, 0, stream>>>(x0p, np4, f, g, eps, inv_eps, logw);
  }

  assign_mlp_kernel<<<B_*(N_/8), 256, 0, stream>>>(np4, x0p, g, t, W1, Wt, b1, W2, b2w, out);
}

// Round 2
// 415.881 us; speedup vs baseline: 1.2105x; 1.2105x over previous
//
#include <hip/hip_runtime.h>
#include <math.h>

#define B_ 8
#define N_ 2048
#define D_ 3
#define H_ 256
#define ND_ (N_*D_)     // 6144
#define BN_ (B_*N_)     // 16384

// ---------------- per-batch std (ddof=1) ----------------
__global__ __launch_bounds__(256) void std_kernel(const float* __restrict__ cloud,
                                                  float* __restrict__ stdv) {
  __shared__ float red[256];
  int b = blockIdx.x, tid = threadIdx.x;
  const float* p = cloud + (size_t)b * ND_;
  float s = 0.f;
  for (int i = tid; i < ND_; i += 256) s += p[i];
  red[tid] = s; __syncthreads();
  for (int off = 128; off > 0; off >>= 1) {
    if (tid < off) red[tid] += red[tid + off];
    __syncthreads();
  }
  float mean = red[0] / (float)ND_;
  __syncthreads();
  float ss = 0.f;
  for (int i = tid; i < ND_; i += 256) { float d = p[i] - mean; ss += d * d; }
  red[tid] = ss; __syncthreads();
  for (int off = 128; off > 0; off >>= 1) {
    if (tid < off) red[tid] += red[tid + off];
    __syncthreads();
  }
  if (tid == 0) stdv[b] = sqrtf(red[0] / (float)(ND_ - 1));
}

// ---------------- pack points as (x,y,z,|p|^2), zero potentials ----------------
__global__ __launch_bounds__(256) void prep_kernel(const float* __restrict__ cloud,
    const float* __restrict__ noise, const float* __restrict__ stdv,
    float4* __restrict__ x0p, float4* __restrict__ np4,
    float* __restrict__ f, float* __restrict__ g) {
  int i = blockIdx.x * 256 + threadIdx.x;
  if (i >= BN_) return;
  int b = i >> 11;
  float sd = stdv[b];
  float cx = cloud[3*i] / sd, cy = cloud[3*i+1] / sd, cz = cloud[3*i+2] / sd;
  x0p[i] = make_float4(cx, cy, cz, cx*cx + cy*cy + cz*cz);
  float ax = noise[3*i], ay = noise[3*i+1], az = noise[3*i+2];
  np4[i] = make_float4(ax, ay, az, ax*ax + ay*ay + az*az);
  f[i] = 0.f; g[i] = 0.f;
}

// ---------------- one Sinkhorn half-iteration (log2 domain) ----------------
// exponent arg (base-2) for row i, col j:
//   a2 = log2e*(pot_j - 0.5*sq_ij)/eps = q_j + dot(s*Pxyz_j, s*Axyz_i) + rc_i
// with k=log2e/eps, hh=k/2, s=sqrt(k), q_j = k*pot_j - hh*|p_j|^2, rc_i = -hh*|A_i|^2.
// (clamp max(sq,0) dropped: only differs when fp rounding gives sq<0, i.e. pairs at
//  distance <~3e-4 — probability ~1e-5 over all pairs; argmin kernel keeps the clamp.)
// lse folds rc at the end: pout = c1*(rc + m + log2(sum)) + c2,
//   c1 = -eps*ln2, c2 = -eps*logw.
// block = 256 threads (4 waves); 16 rows/block; wave -> 4 rows; lanes over j.
__global__ __launch_bounds__(256, 2) void lse_kernel(
    const float4* __restrict__ outer, const float4* __restrict__ inner,
    const float* __restrict__ pin, float* __restrict__ pout,
    float scl, float kk, float hh, float c1, float c2) {
  __shared__ float4 sP[N_];   // 32 KB: scaled coords + q
  int tid = threadIdx.x;
  int b = blockIdx.x >> 7;                 // 128 blocks per batch
  int rowBase = (blockIdx.x & 127) << 4;   // 16 rows per block
  int base = b * N_;
  for (int j = tid; j < N_; j += 256) {
    float4 p = inner[base + j];
    float q = kk * pin[base + j] - hh * p.w;
    sP[j] = make_float4(scl * p.x, scl * p.y, scl * p.z, q);
  }
  __syncthreads();
  int wave = tid >> 6, lane = tid & 63;
  int r0 = base + rowBase + (wave << 2);
  float4 A0 = outer[r0], A1 = outer[r0+1], A2 = outer[r0+2], A3 = outer[r0+3];
  float a0x = scl*A0.x, a0y = scl*A0.y, a0z = scl*A0.z, rc0 = -hh*A0.w;
  float a1x = scl*A1.x, a1y = scl*A1.y, a1z = scl*A1.z, rc1 = -hh*A1.w;
  float a2x = scl*A2.x, a2y = scl*A2.y, a2z = scl*A2.z, rc2 = -hh*A2.w;
  float a3x = scl*A3.x, a3y = scl*A3.y, a3z = scl*A3.z, rc3 = -hh*A3.w;
  float v0[32], v1[32], v2[32], v3[32];
  float m0 = -INFINITY, m1 = -INFINITY, m2 = -INFINITY, m3 = -INFINITY;
#pragma unroll
  for (int jj = 0; jj < 32; ++jj) {
    float4 p = sP[(jj << 6) + lane];
    float t0 = fmaf(p.x, a0x, p.w); t0 = fmaf(p.y, a0y, t0); t0 = fmaf(p.z, a0z, t0);
    v0[jj] = t0; m0 = fmaxf(m0, t0);
    float t1 = fmaf(p.x, a1x, p.w); t1 = fmaf(p.y, a1y, t1); t1 = fmaf(p.z, a1z, t1);
    v1[jj] = t1; m1 = fmaxf(m1, t1);
    float t2 = fmaf(p.x, a2x, p.w); t2 = fmaf(p.y, a2y, t2); t2 = fmaf(p.z, a2z, t2);
    v2[jj] = t2; m2 = fmaxf(m2, t2);
    float t3 = fmaf(p.x, a3x, p.w); t3 = fmaf(p.y, a3y, t3); t3 = fmaf(p.z, a3z, t3);
    v3[jj] = t3; m3 = fmaxf(m3, t3);
  }
#pragma unroll
  for (int off = 32; off >= 1; off >>= 1) {
    m0 = fmaxf(m0, __shfl_xor(m0, off, 64));
    m1 = fmaxf(m1, __shfl_xor(m1, off, 64));
    m2 = fmaxf(m2, __shfl_xor(m2, off, 64));
    m3 = fmaxf(m3, __shfl_xor(m3, off, 64));
  }
  float s0 = 0.f, s1 = 0.f, s2 = 0.f, s3 = 0.f;
#pragma unroll
  for (int jj = 0; jj < 32; ++jj) {
    s0 += __builtin_amdgcn_exp2f(v0[jj] - m0);
    s1 += __builtin_amdgcn_exp2f(v1[jj] - m1);
    s2 += __builtin_amdgcn_exp2f(v2[jj] - m2);
    s3 += __builtin_amdgcn_exp2f(v3[jj] - m3);
  }
#pragma unroll
  for (int off = 32; off >= 1; off >>= 1) {
    s0 += __shfl_xor(s0, off, 64);
    s1 += __shfl_xor(s1, off, 64);
    s2 += __shfl_xor(s2, off, 64);
    s3 += __shfl_xor(s3, off, 64);
  }
  if (lane == 0) {
    pout[r0]   = fmaf(c1, rc0 + m0 + __builtin_amdgcn_logf(s0), c2);
    pout[r0+1] = fmaf(c1, rc1 + m1 + __builtin_amdgcn_logf(s1), c2);
    pout[r0+2] = fmaf(c1, rc2 + m2 + __builtin_amdgcn_logf(s2), c2);
    pout[r0+3] = fmaf(c1, rc3 + m3 + __builtin_amdgcn_logf(s3), c2);
  }
}

// ---------------- fused argmin(sqdist - g) + gather + interp + MLP ----------------
__global__ __launch_bounds__(256) void assign_mlp_kernel(
    const float4* __restrict__ np4, const float4* __restrict__ x0p,
    const float* __restrict__ g, const float* __restrict__ t,
    const float* __restrict__ W1, const float* __restrict__ Wt,
    const float* __restrict__ b1, const float* __restrict__ W2,
    const float* __restrict__ b2, float* __restrict__ out) {
  __shared__ float4 sPts[N_];                 // x0 points
  __shared__ float  sg[N_];
  __shared__ float  sW1[3*H_], sWt[H_], sb1[H_], sW2[H_*3], sb2[3];
  int tid = threadIdx.x;
  int b = blockIdx.x >> 8;
  int rowBase = (blockIdx.x & 255) << 3;
  int base = b * N_;
  for (int j = tid; j < N_; j += 256) { sPts[j] = x0p[base+j]; sg[j] = g[base+j]; }
  for (int i = tid; i < 3*H_; i += 256) { sW1[i] = W1[i]; sW2[i] = W2[i]; }
  if (tid < H_) { sWt[tid] = Wt[tid]; sb1[tid] = b1[tid]; }
  if (tid < 3) sb2[tid] = b2[tid];
  __syncthreads();
  int wave = tid >> 6, lane = tid & 63;
  float tb = t[b];
  for (int rr = 0; rr < 2; ++rr) {
    int r = rowBase + (wave << 1) + rr;
    float4 A = np4[base + r];
    float best = INFINITY; int bidx = 0;
#pragma unroll
    for (int jj = 0; jj < 32; ++jj) {
      int j = (jj << 6) + lane;
      float4 p = sPts[j];
      float d = A.x*p.x + A.y*p.y + A.z*p.z;
      float val = fmaxf(A.w + p.w - 2.0f*d, 0.0f) - sg[j];
      if (val < best) { best = val; bidx = j; }   // strict < keeps lowest j per lane
    }
#pragma unroll
    for (int off = 32; off >= 1; off >>= 1) {
      float ov = __shfl_xor(best, off, 64);
      int   oi = __shfl_xor(bidx, off, 64);
      if (ov < best || (ov == best && oi < bidx)) { best = ov; bidx = oi; }
    }
    float4 xa = sPts[bidx];
    float xtx = (1.0f - tb)*xa.x + tb*A.x;
    float xty = (1.0f - tb)*xa.y + tb*A.y;
    float xtz = (1.0f - tb)*xa.z + tb*A.z;
    float acc0 = 0.f, acc1 = 0.f, acc2 = 0.f;
#pragma unroll
    for (int hh = 0; hh < 4; ++hh) {
      int h = (hh << 6) + lane;
      float hv = xtx*sW1[h] + xty*sW1[H_+h] + xtz*sW1[2*H_+h] + tb*sWt[h] + sb1[h];
      hv = fmaxf(hv, 0.0f);
      acc0 += hv * sW2[3*h];
      acc1 += hv * sW2[3*h+1];
      acc2 += hv * sW2[3*h+2];
    }
#pragma unroll
    for (int off = 32; off >= 1; off >>= 1) {
      acc0 += __shfl_xor(acc0, off, 64);
      acc1 += __shfl_xor(acc1, off, 64);
      acc2 += __shfl_xor(acc2, off, 64);
    }
    if (lane == 0) {
      int gi = base + r;
      out[3*gi]   = acc0 + sb2[0];
      out[3*gi+1] = acc1 + sb2[1];
      out[3*gi+2] = acc2 + sb2[2];
      out[3*BN_ + 3*gi]   = A.x - xa.x;
      out[3*BN_ + 3*gi+1] = A.y - xa.y;
      out[3*BN_ + 3*gi+2] = A.z - xa.z;
    }
  }
}

extern "C" void kernel_launch(void* const* d_in, const int* in_sizes, int n_in,
                              void* d_out, int out_size, void* d_ws, size_t ws_size,
                              hipStream_t stream) {
  (void)in_sizes; (void)n_in; (void)out_size; (void)ws_size;
  const float* cloud = (const float*)d_in[0];
  const float* noise = (const float*)d_in[1];
  const float* t     = (const float*)d_in[2];
  const float* W1    = (const float*)d_in[3];
  const float* Wt    = (const float*)d_in[4];
  const float* b1    = (const float*)d_in[5];
  const float* W2    = (const float*)d_in[6];
  const float* b2w   = (const float*)d_in[7];
  float* out = (float*)d_out;

  float* ws   = (float*)d_ws;
  float* stdv = ws;                         // 8 floats (pad to 16)
  float4* x0p = (float4*)(ws + 16);         // BN_ float4
  float4* np4 = (float4*)(ws + 16 + 4*BN_); // BN_ float4
  float* f    = ws + 16 + 8*BN_;            // BN_
  float* g    = f + BN_;                    // BN_

  std_kernel<<<B_, 256, 0, stream>>>(cloud, stdv);
  prep_kernel<<<BN_/256, 256, 0, stream>>>(cloud, noise, stdv, x0p, np4, f, g);

  const double LOG2E = 1.4426950408889634074;
  const double LN2   = 0.6931471805599453094;
  const double logw  = -log(2048.0);          // loga == logb == -log(N)
  const double l0 = log10(32.0), l1 = log10(1e-6);
  for (int kit = 0; kit < 14; ++kit) {
    // np.geomspace(32, 1e-6, 14) == 10**linspace(log10(32), -6, 14), cast fp32
    double epsd = pow(10.0, l0 + (l1 - l0) * ((double)kit / 13.0));
    float eps = (float)epsd;
    float kk  = (float)(LOG2E / (double)eps);
    float hh  = 0.5f * kk;
    float scl = sqrtf(kk);
    float c1  = (float)(-(double)eps * LN2);
    float c2  = (float)(-(double)eps * logw);
    // f = -eps*lse_j(logb + (g - C)/eps): rows = noise, inner = x0/g
    lse_kernel<<<B_*(N_/16), 256, 0, stream>>>(np4, x0p, g, f, scl, kk, hh, c1, c2);
    // g = -eps*lse_i(loga + (f - C)/eps): rows = x0, inner = noise/f
    lse_kernel<<<B_*(N_/16), 256, 0, stream>>>(x0p, np4, f, g, scl, kk, hh, c1, c2);
  }

  assign_mlp_kernel<<<B_*(N_/8), 256, 0, stream>>>(np4, x0p, g, t, W1, Wt, b1, W2, b2w, out);
}